// Round 5
// baseline (34283.359 us; speedup 1.0000x reference)
//
#include <hip/hip_runtime.h>
#include <math.h>

#define KW 24
#define BSZn 64
#define PLY 32
#define BROWS 1536            // BSZ*KW rows per task
#define RTOT 4608             // 3*BROWS

__device__ __forceinline__ float sigmoidf_(float x) { return 1.0f / (1.0f + expf(-x)); }

// ---- prep: W3T[1024][2048] (gate cols interleaved i,f,g,o), WqT[512][512],
// ----       WcT[512][512], biasg[2048] ----
__global__ void prep_kernel(const float* __restrict__ W_ih, const float* __restrict__ W_hh,
                            const float* __restrict__ Wq, const float* __restrict__ Wc,
                            const float* __restrict__ b_ih, const float* __restrict__ b_hh,
                            float* __restrict__ W3T, float* __restrict__ WqT,
                            float* __restrict__ WcT, float* __restrict__ biasg)
{
    int k = blockIdx.x, tid = threadIdx.x;       // k: 0..1023
    for (int n = tid; n < 2048; n += 256) {
        int src = (n & 3) * 512 + (n >> 2);      // gate-interleaved source row
        W3T[(size_t)k * 2048 + n] =
            (k < 512) ? W_ih[(size_t)src * 512 + k] : W_hh[(size_t)src * 512 + (k - 512)];
    }
    if (k < 512) {
        for (int n = tid; n < 512; n += 256) {
            WqT[(size_t)k * 512 + n] = Wq[(size_t)n * 512 + k];
            WcT[(size_t)k * 512 + n] = Wc[(size_t)n * 512 + k];
        }
    }
    if (k == 0) {
        for (int n = tid; n < 2048; n += 256) {
            int src = (n & 3) * 512 + (n >> 2);
            biasg[n] = b_ih[src] + b_hh[src];
        }
    }
}

// ---- h0 = enc.sum(axis=1) -> hbuf0 and cst ----
__global__ void h0init_kernel(const float* __restrict__ home, const float* __restrict__ vis,
                              const float* __restrict__ team,
                              float* __restrict__ hbuf0, float* __restrict__ cst)
{
    int row = blockIdx.x;                 // 0..4607
    int tid = threadIdx.x;                // 256
    int tau = row / BROWS, r = row % BROWS;
    int bb = r / KW, kw = r % KW;
    const float* enc = (tau == 0) ? home : (tau == 1) ? vis : team;
    const float* base = enc + ((size_t)(kw * BSZn + bb) * PLY) * 512;
    for (int e = tid; e < 512; e += blockDim.x) {
        float s = 0.0f;
        for (int p = 0; p < PLY; ++p) s += base[(size_t)p * 512 + e];
        hbuf0[(size_t)row * 512 + e] = s;
        cst[(size_t)row * 512 + e] = s;
    }
}

// ---- ctx = enc @ Wc^T, scalar-B GEMM: block 64 rows x 64 cols, 256 thr ----
__global__ __launch_bounds__(256, 8) void ctx_kernel(
    const float* __restrict__ home, const float* __restrict__ vis, const float* __restrict__ team,
    const float* __restrict__ WcT, float* __restrict__ ctx)
{
    __shared__ float AsT[2][32][65];
    int bid = blockIdx.x;                 // 18432 = 2304 panels * 8 col-blocks
    int bm = bid >> 3, bn = bid & 7;
    int tid = threadIdx.x;
    int wv = tid >> 6, lane = tid & 63;
    int lrow = tid >> 2, lc = tid & 3;

    int crow = bm * 64 + lrow;
    int R = crow >> 5, p = crow & 31;
    int tau = (bm * 64) / (BROWS * PLY);
    const float* enc = (tau == 0) ? home : (tau == 1) ? vis : team;
    int r = R - tau * BROWS;
    const float* aptr = enc + (((size_t)((r % KW) * BSZn + r / KW)) * PLY + p) * 512;

    int c0 = __builtin_amdgcn_readfirstlane(bn * 4 + wv) * 16;   // uniform, 16-aligned
    float acc[16];
    #pragma unroll
    for (int j = 0; j < 16; ++j) acc[j] = 0.0f;

    float4 ra = *(const float4*)(aptr + lc * 4);
    float4 rb = *(const float4*)(aptr + 16 + lc * 4);

    for (int tile = 0; tile < 16; ++tile) {
        int buf = tile & 1;
        #pragma unroll
        for (int i = 0; i < 4; ++i) AsT[buf][lc * 4 + i][lrow] = ((const float*)&ra)[i];
        #pragma unroll
        for (int i = 0; i < 4; ++i) AsT[buf][16 + lc * 4 + i][lrow] = ((const float*)&rb)[i];
        __syncthreads();
        if (tile + 1 < 16) {
            int k0 = (tile + 1) * 32;
            ra = *(const float4*)(aptr + k0 + lc * 4);
            rb = *(const float4*)(aptr + k0 + 16 + lc * 4);
        }
        const float* brow = WcT + (size_t)(tile * 32) * 512 + c0;
        #pragma unroll
        for (int kk = 0; kk < 32; ++kk) {
            float a = AsT[buf][kk][lane];
            const float* bp = brow + (size_t)kk * 512;
            #pragma unroll
            for (int j = 0; j < 16; ++j) acc[j] = fmaf(a, bp[j], acc[j]);
        }
        __syncthreads();
    }
    float* cr = ctx + (size_t)(bm * 64 + lane) * 512 + c0;
    #pragma unroll
    for (int i = 0; i < 4; ++i) {
        float4 o; o.x = acc[4*i]; o.y = acc[4*i+1]; o.z = acc[4*i+2]; o.w = acc[4*i+3];
        *(float4*)(cr + 4 * i) = o;
    }
}

// ---- mega step kernel: gate blocks | q blocks | attn blocks ----
// gates: [gates_t] = [x_t | h_{t-1}] @ W3T + biasg, LSTM fused in epilogue.
// q:     q_{t-1} = h_{t-1} @ WqT + bq -> Q5 slot (t-1)%5.
// attn:  batched 4-step attention for tbase..tbase+3 (reads older Q5 slots).
__global__ __launch_bounds__(256, 8) void step_k(
    const float* __restrict__ home, const float* __restrict__ vis, const float* __restrict__ team,
    const int* __restrict__ hidx, const int* __restrict__ vidx, const int* __restrict__ tidx,
    const float* __restrict__ init_embed,
    const float* __restrict__ W3T, const float* __restrict__ WqT,
    const float* __restrict__ biasg, const float* __restrict__ bq,
    const float* __restrict__ hin, float* __restrict__ hout,
    float* __restrict__ cst, float* __restrict__ Q5,
    const float* __restrict__ ctx, const float* __restrict__ vvec,
    float* __restrict__ out,
    int t, int ng, int nq, int tbase)
{
    __shared__ float AsT[2][32][65];
    __shared__ float scs[4][32];
    int bid = blockIdx.x, tid = threadIdx.x;

    if (bid < ng + nq) {
        bool isg = bid < ng;
        int bm, cb, Kt, ldb;
        const float* BT;
        if (isg) { bm = bid >> 5; cb = (bid & 31); BT = W3T; Kt = 32; ldb = 2048; }
        else { int qb = bid - ng; bm = qb >> 3; cb = (qb & 7); BT = WqT; Kt = 16; ldb = 512; }
        int wv = tid >> 6, lane = tid & 63;
        int lrow = tid >> 2, lc = tid & 3;
        int c0 = __builtin_amdgcn_readfirstlane(cb * 4 + wv) * 16;   // uniform, 16-aligned

        int Rl = bm * 64 + lrow;
        const float* hptr = hin + (size_t)Rl * 512;
        const float* xptr = init_embed;
        if (isg && t > 0) {
            int tau = (bm * 64) / BROWS;
            const float* enc = (tau == 0) ? home : (tau == 1) ? vis : team;
            const int* idx = (tau == 0) ? hidx : (tau == 1) ? vidx : tidx;
            int r = Rl - tau * BROWS;
            int j = idx[r * PLY + (t - 1)];
            xptr = enc + (((size_t)((r % KW) * BSZn + r / KW)) * PLY + j) * 512;
        }

        float acc[16];
        #pragma unroll
        for (int j = 0; j < 16; ++j) acc[j] = 0.0f;

        const float* src0 = isg ? xptr : hptr;
        float4 ra = *(const float4*)(src0 + lc * 4);
        float4 rb = *(const float4*)(src0 + 16 + lc * 4);

        for (int tile = 0; tile < Kt; ++tile) {
            int buf = tile & 1;
            #pragma unroll
            for (int i = 0; i < 4; ++i) AsT[buf][lc * 4 + i][lrow] = ((const float*)&ra)[i];
            #pragma unroll
            for (int i = 0; i < 4; ++i) AsT[buf][16 + lc * 4 + i][lrow] = ((const float*)&rb)[i];
            __syncthreads();
            if (tile + 1 < Kt) {
                int t2 = tile + 1;
                const float* src = (isg && t2 < 16) ? (xptr + t2 * 32)
                                 : (isg ? (hptr + (t2 - 16) * 32) : (hptr + t2 * 32));
                ra = *(const float4*)(src + lc * 4);
                rb = *(const float4*)(src + 16 + lc * 4);
            }
            const float* brow = BT + (size_t)(tile * 32) * ldb + c0;
            #pragma unroll
            for (int kk = 0; kk < 32; ++kk) {
                float a = AsT[buf][kk][lane];
                const float* bp = brow + (size_t)kk * ldb;
                #pragma unroll
                for (int j = 0; j < 16; ++j) acc[j] = fmaf(a, bp[j], acc[j]);
            }
            __syncthreads();
        }

        int R2 = bm * 64 + lane;
        if (isg) {
            int u0 = c0 >> 2;                       // 4 units per lane, 16B aligned
            const float* bgp = biasg + c0;
            float4 c = *(float4*)(cst + (size_t)R2 * 512 + u0);
            float cc[4] = {c.x, c.y, c.z, c.w};
            float4 h;
            float hh[4];
            #pragma unroll
            for (int u = 0; u < 4; ++u) {
                float gi = acc[4*u+0] + bgp[4*u+0];
                float gf = acc[4*u+1] + bgp[4*u+1];
                float gg = acc[4*u+2] + bgp[4*u+2];
                float go = acc[4*u+3] + bgp[4*u+3];
                cc[u] = sigmoidf_(gf) * cc[u] + sigmoidf_(gi) * tanhf(gg);
                hh[u] = sigmoidf_(go) * tanhf(cc[u]);
            }
            c.x = cc[0]; c.y = cc[1]; c.z = cc[2]; c.w = cc[3];
            h.x = hh[0]; h.y = hh[1]; h.z = hh[2]; h.w = hh[3];
            *(float4*)(cst  + (size_t)R2 * 512 + u0) = c;
            *(float4*)(hout + (size_t)R2 * 512 + u0) = h;
        } else {
            int qslot = (t - 1) % 5;
            const float* bqp = bq + c0;
            float* qp = Q5 + ((size_t)R2 * 5 + qslot) * 512 + c0;
            #pragma unroll
            for (int i = 0; i < 4; ++i) {
                float4 o;
                o.x = acc[4*i+0] + bqp[4*i+0];
                o.y = acc[4*i+1] + bqp[4*i+1];
                o.z = acc[4*i+2] + bqp[4*i+2];
                o.w = acc[4*i+3] + bqp[4*i+3];
                *(float4*)(qp + 4 * i) = o;
            }
        }
    } else {
        // ---------------- attention path: 4 waves, wave w -> step tbase+w ----------------
        int row = bid - ng - nq;              // 0..4607
        int w = tid >> 6, lane = tid & 63;
        int tc = tbase + w;
        const float* q = Q5 + ((size_t)row * 5 + (tc % 5)) * 512 + lane * 8;
        const float* ctxr = ctx + ((size_t)row * PLY) * 512 + lane * 8;
        float qv[8], vv[8];
        *(float4*)&qv[0] = *(const float4*)(q);
        *(float4*)&qv[4] = *(const float4*)(q + 4);
        *(float4*)&vv[0] = *(const float4*)(vvec + lane * 8);
        *(float4*)&vv[4] = *(const float4*)(vvec + lane * 8 + 4);

        for (int p = 0; p < PLY; ++p) {
            const float* cp = ctxr + (size_t)p * 512;
            float cv[8];
            *(float4*)&cv[0] = *(const float4*)(cp);
            *(float4*)&cv[4] = *(const float4*)(cp + 4);
            float acc = 0.0f;
            #pragma unroll
            for (int j = 0; j < 8; ++j) acc += tanhf(qv[j] + cv[j]) * vv[j];
            #pragma unroll
            for (int off = 1; off < 64; off <<= 1) acc += __shfl_xor(acc, off);
            if (lane == 0) scs[w][p] = acc;
        }
        __syncthreads();

        if (tid < 128) {
            int w2 = tid >> 5, l = tid & 31;
            float x = scs[w2][l];
            float bvv = x; int bi = l;
            #pragma unroll
            for (int off = 1; off < 32; off <<= 1) {
                float ov = __shfl_xor(bvv, off, 32);
                int oi = __shfl_xor(bi, off, 32);
                if (ov > bvv || (ov == bvv && oi < bi)) { bvv = ov; bi = oi; }
            }
            float s = expf(x - bvv);
            #pragma unroll
            for (int off = 1; off < 32; off <<= 1) s += __shfl_xor(s, off, 32);
            float lse = logf(s);
            int tt = tbase + w2;
            int tau = row / BROWS, r = row % BROWS;
            out[(size_t)tau * (BROWS * 1024) + (size_t)r * 1024 + tt * 32 + l] = x - bvv - lse;
            if (l == 0)
                out[(size_t)3 * (BROWS * 1024) + (size_t)tau * (BROWS * 32) + r * 32 + tt] = (float)bi;
        }
    }
}

extern "C" void kernel_launch(void* const* d_in, const int* in_sizes, int n_in,
                              void* d_out, int out_size, void* d_ws, size_t ws_size,
                              hipStream_t stream)
{
    const float* home = (const float*)d_in[0];
    const int*   hidx = (const int*)d_in[1];
    const float* vis  = (const float*)d_in[2];
    const int*   vidx = (const int*)d_in[3];
    const float* team = (const float*)d_in[4];
    const int*   tidx = (const int*)d_in[5];
    const float* init_embed = (const float*)d_in[6];
    const float* W_ih = (const float*)d_in[7];
    const float* W_hh = (const float*)d_in[8];
    const float* b_ih = (const float*)d_in[9];
    const float* b_hh = (const float*)d_in[10];
    const float* Wq   = (const float*)d_in[11];
    const float* bq   = (const float*)d_in[12];
    const float* Wc   = (const float*)d_in[13];
    const float* vvec = (const float*)d_in[14];
    float* out = (float*)d_out;
    (void)in_sizes; (void)n_in; (void)out_size; (void)ws_size;

    float* ws = (float*)d_ws;
    float* W3T   = ws; ws += (size_t)1024 * 2048;   // 8.4 MB
    float* WqT   = ws; ws += (size_t)512 * 512;
    float* WcT   = ws; ws += (size_t)512 * 512;
    float* biasg = ws; ws += 2048;
    float* hbuf0 = ws; ws += (size_t)RTOT * 512;
    float* hbuf1 = ws; ws += (size_t)RTOT * 512;
    float* cst   = ws; ws += (size_t)RTOT * 512;
    float* Q5    = ws; ws += (size_t)RTOT * 5 * 512; // 47.2 MB
    float* ctx   = ws;                               // 302 MB f32; total 387.98 MB

    const int NG = 2304;   // 72 row-panels x 32 gate col-blocks (64 cols)
    const int NQ = 576;    // 72 x 8 q col-blocks
    const int NA = RTOT;   // attn blocks (1 row x 4 steps each)

    prep_kernel<<<1024, 256, 0, stream>>>(W_ih, W_hh, Wq, Wc, b_ih, b_hh, W3T, WqT, WcT, biasg);
    h0init_kernel<<<RTOT, 256, 0, stream>>>(home, vis, team, hbuf0, cst);
    // FIX(R4): grid was RTOT/64*PLY/2*8 = 9216 (half the panels) — vis/team ctx
    // never computed. Correct: one block per 64-row panel (RTOT*PLY/64 = 2304) x 8.
    ctx_kernel<<<(RTOT * PLY / 64) * 8, 256, 0, stream>>>(home, vis, team, WcT, ctx); // 18432

    for (int t = 0; t <= 32; ++t) {
        int ng = (t < 32) ? NG : 0;
        int nq = (t >= 1) ? NQ : 0;
        int tbase = (t >= 5 && ((t - 5) & 3) == 0) ? (t - 5) : -1;  // t=5,9,...,29
        int na = (tbase >= 0) ? NA : 0;
        const float* hin = (t & 1) ? hbuf1 : hbuf0;
        float* hout = (t & 1) ? hbuf0 : hbuf1;
        step_k<<<ng + nq + na, 256, 0, stream>>>(
            home, vis, team, hidx, vidx, tidx, init_embed,
            W3T, WqT, biasg, bq, hin, hout, cst, Q5, ctx, vvec, out,
            t, ng, nq, tbase);
    }
    // final attention batch: steps 28..31 (q31 written by t=32 kernel, slot 1)
    step_k<<<NA, 256, 0, stream>>>(
        home, vis, team, hidx, vidx, tidx, init_embed,
        W3T, WqT, biasg, bq, hbuf0, hbuf1, cst, Q5, ctx, vvec, out,
        33, 0, 0, 28);
}